// Round 1
// baseline (263.367 us; speedup 1.0000x reference)
//
#include <hip/hip_runtime.h>
#include <hip/hip_bf16.h>

#define C 256
#define HW 4096
#define REP_ROW 528           // elems per replica row (covers e up to 527)
#define LDSK 264              // act tile row stride in bf16 elems (256 + 8 pad -> 528B, 16B aligned)

typedef __attribute__((ext_vector_type(8))) short short8;
typedef __attribute__((ext_vector_type(4))) float float4v;

__device__ __forceinline__ unsigned short f2bf(float x) {
    unsigned u = __builtin_bit_cast(unsigned, x);
    u = (u + 0x7fffu + ((u >> 16) & 1u)) >> 16;
    return (unsigned short)u;
}

// Kernel 1: one block. Build g = IDFT(1/(1 - DFT(kernel))) in fp64, then write the
// 8-way rotated bf16 replica table rep[t][u] = bf16(grev[(u+t)%256]), grev[d]=g[(-d)%256].
__global__ void build_rep_kernel(const float* __restrict__ filt, unsigned short* __restrict__ rep) {
    __shared__ double twc[256], tws[256];
    __shared__ double Gre[256], Gim[256];
    __shared__ float gsh[256];
    const int t = threadIdx.x;
    const double PI = 3.14159265358979323846;
    double th = (double)t * (PI / 128.0);      // 2*pi*t/256
    twc[t] = cos(th);
    tws[t] = sin(th);
    __syncthreads();
    // m_hat[f] = 1 - sum_i filt[i] * e^{-2pi i f d_i/256},  d_i = (243+i)%256  (pad_roll layout)
    double re = 1.0, im = 0.0;
    for (int i = 0; i < 27; ++i) {
        int d = (243 + i) & 255;
        int idx = (t * d) & 255;
        double fv = (double)filt[i];
        re -= fv * twc[idx];
        im += fv * tws[idx];
    }
    double den = re * re + im * im;
    Gre[t] = re / den;
    Gim[t] = -im / den;
    __syncthreads();
    // g[d] = (1/256) sum_f Re(G[f] e^{+2pi i f d/256})
    double acc = 0.0;
    for (int f = 0; f < 256; ++f) {
        int idx = (f * t) & 255;
        acc += Gre[f] * twc[idx] - Gim[f] * tws[idx];
    }
    gsh[t] = (float)(acc * (1.0 / 256.0));
    __syncthreads();
    for (int e = t; e < 8 * REP_ROW; e += 256) {
        int tt = e / REP_ROW, u = e % REP_ROW;
        int src = (4096 - u - tt) & 255;       // grev[(u+tt)%256] = g[(-(u+tt))%256]
        rep[e] = f2bf(gsh[src]);
    }
}

// Kernel 2: out[c,p] = sum_k W[c,k]*act[k,p], W circulant from rep table.
// Block: full 256 c x 64 pixels. 4 waves; wave w owns c in [64w, 64w+64).
__global__ __launch_bounds__(256, 2)
void toeplitz_gemm_kernel(const float* __restrict__ act,
                          const unsigned short* __restrict__ rep_g,
                          float* __restrict__ out) {
    __shared__ unsigned short rep[8 * REP_ROW];    //  8448 B
    __shared__ unsigned short atile[64 * LDSK];    // 33792 B  (atile[p][k] = bf16(act[k][p0+p]))

    const int tid = threadIdx.x;
    const int wave = tid >> 6;
    const int lane = tid & 63;
    const int m = lane & 15;        // MFMA row (A) / col (B,D) index
    const int quad = lane >> 4;     // k-subchunk selector
    const int blk = blockIdx.x;
    const int n = blk >> 6;                 // 64 blocks per image (4096/64)
    const int p0 = (blk & 63) << 6;         // pixel offset within image
    const float* actn = act + (size_t)n * (C * HW);
    float* outn = out + (size_t)n * (C * HW);

    // ---- load replica table into LDS (528 uint4) ----
    {
        const uint4* rg = (const uint4*)rep_g;
        uint4* rl = (uint4*)rep;
        for (int i = tid; i < (8 * REP_ROW * 2) / 16; i += 256) rl[i] = rg[i];
    }

    // ---- stage act tile: global [k][p] fp32 -> LDS [p][k] bf16 (4x4 register transpose) ----
    {
        const int kb = (tid & 15) << 2;   // k sub-base within 64-chunk
        const int pb = (tid >> 4) << 2;   // p base
#pragma unroll
        for (int it = 0; it < 4; ++it) {
            const int ks = it * 64 + kb;
            const float* g0 = actn + (size_t)ks * HW + p0 + pb;
            float4v r0 = *(const float4v*)(g0);
            float4v r1 = *(const float4v*)(g0 + HW);
            float4v r2 = *(const float4v*)(g0 + 2 * HW);
            float4v r3 = *(const float4v*)(g0 + 3 * HW);
#pragma unroll
            for (int pp = 0; pp < 4; ++pp) {
                unsigned long long pk =
                      (unsigned long long)f2bf(r0[pp])
                    | ((unsigned long long)f2bf(r1[pp]) << 16)
                    | ((unsigned long long)f2bf(r2[pp]) << 32)
                    | ((unsigned long long)f2bf(r3[pp]) << 48);
                *(unsigned long long*)&atile[(pb + pp) * LDSK + ks] = pk;
            }
        }
    }
    __syncthreads();

    // ---- preload the 16 distinct circulant A-fragments for this wave ----
    // afrag[f] holds W-fragment with shift s = 16*((f - 4*wave) mod 16); use site f = (2a - ct) mod 16.
    short8 afrag[16];
#pragma unroll
    for (int f = 0; f < 16; ++f) {
        int s = ((f - 4 * wave) & 15) << 4;
        int e = s + 256 + quad * 8 - m;        // in [241, 520]
        int tt = e & 7, q = e >> 3;
        afrag[f] = *(const short8*)&rep[tt * REP_ROW + q * 8];  // 16B-aligned ds_read_b128
    }

    float4v acc[4][4];
#pragma unroll
    for (int ct = 0; ct < 4; ++ct)
#pragma unroll
        for (int pt = 0; pt < 4; ++pt)
            acc[ct][pt] = (float4v){0.f, 0.f, 0.f, 0.f};

    // ---- K-loop: 8 steps of 32, 16 MFMAs each ----
#pragma unroll
    for (int a = 0; a < 8; ++a) {
        const int k0 = a * 32;
        short8 bfr[4];
#pragma unroll
        for (int pt = 0; pt < 4; ++pt) {
            const int prow = pt * 16 + m;
            bfr[pt] = *(const short8*)&atile[prow * LDSK + k0 + quad * 8];  // ds_read_b128
        }
#pragma unroll
        for (int ct = 0; ct < 4; ++ct) {
            const int f = (2 * a - ct) & 15;
#pragma unroll
            for (int pt = 0; pt < 4; ++pt) {
                acc[ct][pt] = __builtin_amdgcn_mfma_f32_16x16x32_bf16(
                    afrag[f], bfr[pt], acc[ct][pt], 0, 0, 0);
            }
        }
    }

    // ---- epilogue: D layout col=lane&15, row=quad*4+r ----
#pragma unroll
    for (int ct = 0; ct < 4; ++ct) {
#pragma unroll
        for (int r = 0; r < 4; ++r) {
            const int c = wave * 64 + ct * 16 + quad * 4 + r;
            float* op = outn + (size_t)c * HW + p0;
#pragma unroll
            for (int pt = 0; pt < 4; ++pt) {
                op[pt * 16 + m] = acc[ct][pt][r];
            }
        }
    }
}

extern "C" void kernel_launch(void* const* d_in, const int* in_sizes, int n_in,
                              void* d_out, int out_size, void* d_ws, size_t ws_size,
                              hipStream_t stream) {
    const float* act = (const float*)d_in[0];
    const float* filt = (const float*)d_in[1];
    float* out = (float*)d_out;
    unsigned short* rep = (unsigned short*)d_ws;   // 8448 bytes used

    build_rep_kernel<<<1, 256, 0, stream>>>(filt, rep);
    toeplitz_gemm_kernel<<<2048, 256, 0, stream>>>(act, rep, out);
}

// Round 2
// 256.165 us; speedup vs baseline: 1.0281x; 1.0281x over previous
//
#include <hip/hip_runtime.h>
#include <hip/hip_bf16.h>

#define C 256
#define HW 4096
#define REP_ROW 288           // compacted replica row: covers elems e-240 in [0,288)
#define LDSK 264              // act tile row stride in bf16 elems (256 + 8 pad -> 528B, 16B aligned)

typedef __attribute__((ext_vector_type(8))) short short8;
typedef __attribute__((ext_vector_type(4))) float float4v;

__device__ __forceinline__ unsigned short f2bf(float x) {
    unsigned u = __builtin_bit_cast(unsigned, x);
    u = (u + 0x7fffu + ((u >> 16) & 1u)) >> 16;
    return (unsigned short)u;
}

// Kernel 1: one block. g = IDFT(1/(1 - DFT(kernel))), then compacted 8-way rotated
// bf16 replica table: rep[row*288 + u] = bf16(g[(16 - u - row) & 255]), row<8, u<288.
__global__ void build_rep_kernel(const float* __restrict__ filt, unsigned short* __restrict__ rep) {
    __shared__ float twc[256], tws[256];
    __shared__ float Gre[256], Gim[256];
    __shared__ float gsh[256];
    const int t = threadIdx.x;
    const double PI = 3.14159265358979323846;
    double th = (double)t * (PI / 128.0);      // 2*pi*t/256
    twc[t] = (float)cos(th);
    tws[t] = (float)sin(th);
    __syncthreads();
    // m_hat[f] = 1 - sum_i filt[i] * e^{-2pi i f d_i/256},  d_i = (243+i)%256  (pad_roll layout)
    float re = 1.0f, im = 0.0f;
    for (int i = 0; i < 27; ++i) {
        int d = (243 + i) & 255;
        int idx = (t * d) & 255;
        float fv = filt[i];
        re -= fv * twc[idx];
        im += fv * tws[idx];
    }
    float den = re * re + im * im;
    Gre[t] = re / den;
    Gim[t] = -im / den;
    __syncthreads();
    // g[d] = (1/256) sum_f Re(G[f] e^{+2pi i f d/256})
    float acc = 0.0f;
    for (int f = 0; f < 256; ++f) {
        int idx = (f * t) & 255;
        acc += Gre[f] * twc[idx] - Gim[f] * tws[idx];
    }
    gsh[t] = acc * (1.0f / 256.0f);
    __syncthreads();
    for (int e = t; e < 8 * REP_ROW; e += 256) {
        int row = e / REP_ROW, u = e - row * REP_ROW;
        int src = (16 - u - row) & 255;        // grev[(240+u+row)%256] = g[(-(240+u+row))%256]
        rep[e] = f2bf(gsh[src]);
    }
}

// Kernel 2: out[c,p] = sum_k W[c,k]*act[k,p], W circulant from compacted rep table.
// Block: full 256 c x 64 pixels. 4 waves; wave w owns c in [64w, 64w+64).
__global__ __launch_bounds__(256, 3)
void toeplitz_gemm_kernel(const float* __restrict__ act,
                          const unsigned short* __restrict__ rep_g,
                          float* __restrict__ out) {
    __shared__ unsigned short rep2[8 * REP_ROW];   //  4608 B
    __shared__ unsigned short atile[64 * LDSK];    // 33792 B  (atile[p][k] = bf16(act[k][p0+p]))

    const int tid = threadIdx.x;
    const int wave = tid >> 6;
    const int lane = tid & 63;
    const int m = lane & 15;        // MFMA row (A) / col (B,D) index
    const int quad = lane >> 4;     // k-subchunk selector
    const int blk = blockIdx.x;
    const int n = blk >> 6;                 // 64 blocks per image (4096/64)
    const int p0 = (blk & 63) << 6;         // pixel offset within image
    const float* actn = act + (size_t)n * (C * HW);
    float* outn = out + (size_t)n * (C * HW);

    // ---- copy compacted replica table into LDS (288 uint4) ----
    {
        const uint4* rg = (const uint4*)rep_g;
        uint4* rl = (uint4*)rep2;
        for (int i = tid; i < (8 * REP_ROW * 2) / 16; i += 256) rl[i] = rg[i];
    }

    // ---- stage act tile: global [k][p] fp32 -> LDS [p][k] bf16 ----
    // 2 rounds; each round issues 8 float4 loads back-to-back (deep MLP), then packs.
    {
        const int kb = (tid & 15) << 2;   // k sub-base within 64-chunk
        const int pb = (tid >> 4) << 2;   // p base
#pragma unroll
        for (int half = 0; half < 2; ++half) {
            float4v r[8];
#pragma unroll
            for (int it = 0; it < 2; ++it) {
                const int ks = (half * 2 + it) * 64 + kb;
                const float* g0 = actn + (size_t)ks * HW + p0 + pb;
#pragma unroll
                for (int j = 0; j < 4; ++j)
                    r[it * 4 + j] = *(const float4v*)(g0 + (size_t)j * HW);
            }
#pragma unroll
            for (int it = 0; it < 2; ++it) {
                const int ks = (half * 2 + it) * 64 + kb;
#pragma unroll
                for (int pp = 0; pp < 4; ++pp) {
                    unsigned long long pk =
                          (unsigned long long)f2bf(r[it * 4 + 0][pp])
                        | ((unsigned long long)f2bf(r[it * 4 + 1][pp]) << 16)
                        | ((unsigned long long)f2bf(r[it * 4 + 2][pp]) << 32)
                        | ((unsigned long long)f2bf(r[it * 4 + 3][pp]) << 48);
                    *(unsigned long long*)&atile[(pb + pp) * LDSK + ks] = pk;
                }
            }
        }
    }
    __syncthreads();

    // A-fragment address base: fragment f needs grev[e..e+7], e = 256 + 16*s' + quad*8 - m,
    // s' = (f - 4*wave) & 15. Compacted table: elem addr = row*287 + 16 + quad*8 - m + 16*s',
    // row = (-m) & 7. Always 16B-aligned.
    const int arow = (-m) & 7;
    const int abase = arow * 287 + 16 + quad * 8 - m;

    float4v acc[4][4];
#pragma unroll
    for (int ct = 0; ct < 4; ++ct)
#pragma unroll
        for (int pt = 0; pt < 4; ++pt)
            acc[ct][pt] = (float4v){0.f, 0.f, 0.f, 0.f};

    // ---- K-loop: 8 steps of 32; per step 4 B-fragments + 4 A-fragments from LDS, 16 MFMAs ----
#pragma unroll
    for (int a = 0; a < 8; ++a) {
        const int k0 = a * 32;
        short8 bfr[4];
#pragma unroll
        for (int pt = 0; pt < 4; ++pt) {
            const int prow = pt * 16 + m;
            bfr[pt] = *(const short8*)&atile[prow * LDSK + k0 + quad * 8];  // ds_read_b128
        }
        short8 afr[4];
#pragma unroll
        for (int ct = 0; ct < 4; ++ct) {
            const int f = (2 * a - ct) & 15;
            const int sp = (f - 4 * wave) & 15;     // wave-uniform
            afr[ct] = *(const short8*)&rep2[abase + (sp << 4)];  // ds_read_b128
        }
#pragma unroll
        for (int ct = 0; ct < 4; ++ct) {
#pragma unroll
            for (int pt = 0; pt < 4; ++pt) {
                acc[ct][pt] = __builtin_amdgcn_mfma_f32_16x16x32_bf16(
                    afr[ct], bfr[pt], acc[ct][pt], 0, 0, 0);
            }
        }
    }

    // ---- epilogue: D layout col=lane&15, row=quad*4+r ----
#pragma unroll
    for (int ct = 0; ct < 4; ++ct) {
#pragma unroll
        for (int r = 0; r < 4; ++r) {
            const int c = wave * 64 + ct * 16 + quad * 4 + r;
            float* op = outn + (size_t)c * HW + p0;
#pragma unroll
            for (int pt = 0; pt < 4; ++pt) {
                op[pt * 16 + m] = acc[ct][pt][r];
            }
        }
    }
}

extern "C" void kernel_launch(void* const* d_in, const int* in_sizes, int n_in,
                              void* d_out, int out_size, void* d_ws, size_t ws_size,
                              hipStream_t stream) {
    const float* act = (const float*)d_in[0];
    const float* filt = (const float*)d_in[1];
    float* out = (float*)d_out;
    unsigned short* rep = (unsigned short*)d_ws;   // 4608 bytes used

    build_rep_kernel<<<1, 256, 0, stream>>>(filt, rep);
    toeplitz_gemm_kernel<<<2048, 256, 0, stream>>>(act, rep, out);
}

// Round 3
// 250.369 us; speedup vs baseline: 1.0519x; 1.0231x over previous
//
#include <hip/hip_runtime.h>
#include <hip/hip_bf16.h>

#define C 256
#define HW 4096
#define CHUNK_STRIDE 66   // dwords per act row in LDS (64 px + 2 pad) -> 2-way-free bank pattern

typedef __attribute__((ext_vector_type(8))) short short8;
typedef __attribute__((ext_vector_type(4))) float float4v;

__device__ __forceinline__ unsigned short f2bf(float x) {
    unsigned u = __builtin_bit_cast(unsigned, x);
    u = (u + 0x7fffu + ((u >> 16) & 1u)) >> 16;
    return (unsigned short)u;
}

// async global->LDS DMA: 64 lanes x 4B, LDS dst = wave-uniform base + lane*4
__device__ __forceinline__ void g2l_b32(const void* g, void* l) {
    __builtin_amdgcn_global_load_lds(
        (const __attribute__((address_space(1))) unsigned int*)g,
        (__attribute__((address_space(3))) unsigned int*)l, 4, 0, 0);
}
// async global->LDS DMA: 64 lanes x 16B, LDS dst = base + lane*16
__device__ __forceinline__ void g2l_b128(const void* g, void* l) {
    __builtin_amdgcn_global_load_lds(
        (const __attribute__((address_space(1))) unsigned int*)g,
        (__attribute__((address_space(3))) unsigned int*)l, 16, 0, 0);
}

// Kernel 1: one block. g = IDFT(1/(1 - DFT(kernel))), then expanded A-fragment table:
// tab[(s*64 + lane)*8 + j] = bf16(gsh[(m - 16s - 8q - j) & 255]), m=lane&15, q=lane>>4.
// (Same mapping round-2 verified via the rep2 indirection; here written directly.)
__global__ void build_tab_kernel(const float* __restrict__ filt, unsigned short* __restrict__ tab) {
    __shared__ float twc[256], tws[256];
    __shared__ float Gre[256], Gim[256];
    __shared__ float gsh[256];
    const int t = threadIdx.x;
    const double PI = 3.14159265358979323846;
    double th = (double)t * (PI / 128.0);      // 2*pi*t/256
    twc[t] = (float)cos(th);
    tws[t] = (float)sin(th);
    __syncthreads();
    float re = 1.0f, im = 0.0f;
    for (int i = 0; i < 27; ++i) {
        int d = (243 + i) & 255;               // pad_roll layout offsets
        int idx = (t * d) & 255;
        float fv = filt[i];
        re -= fv * twc[idx];
        im += fv * tws[idx];
    }
    float den = re * re + im * im;
    Gre[t] = re / den;
    Gim[t] = -im / den;
    __syncthreads();
    float acc = 0.0f;
    for (int f = 0; f < 256; ++f) {
        int idx = (f * t) & 255;
        acc += Gre[f] * twc[idx] - Gim[f] * tws[idx];
    }
    gsh[t] = acc * (1.0f / 256.0f);
    __syncthreads();
    for (int e = t; e < 16 * 64 * 8; e += 256) {
        int j = e & 7;
        int lane = (e >> 3) & 63;
        int s = e >> 9;
        int m = lane & 15, q = lane >> 4;
        int src = (m - 16 * s - 8 * q - j) & 255;
        tab[e] = f2bf(gsh[src]);
    }
}

// Kernel 2: out[c,p] = sum_k W[c,k]*act[k,p].
// Block: 256 c x 64 px tile. K pipelined in 4 chunks of 64 rows via global_load_lds DMA,
// double-buffered fp32 [k][p] in LDS; bf16 conversion fused into fragment loads.
__global__ __launch_bounds__(256, 3)
void toeplitz_gemm_kernel(const float* __restrict__ act,
                          const unsigned short* __restrict__ tab,
                          float* __restrict__ out) {
    __shared__ float chunkbuf[2][64 * CHUNK_STRIDE];      // 2 x 16896 B
    __shared__ unsigned short afrags[16 * 64 * 8];        // 16384 B

    const int tid = threadIdx.x;
    const int wave = tid >> 6;
    const int lane = tid & 63;
    const int m = lane & 15;        // MFMA row (A) / col (B,D)
    const int quad = lane >> 4;     // k-subchunk selector
    const int blk = blockIdx.x;
    const int n = blk >> 6;                 // 64 px-tiles per image
    const int p0 = (blk & 63) << 6;
    const float* actn = act + (size_t)n * (C * HW);
    float* outn = out + (size_t)n * (C * HW);

    // ---- A-fragment table: 16 KB global -> LDS, 16B/lane DMA (4 rows of 1 KB per wave) ----
#pragma unroll
    for (int i = 0; i < 4; ++i) {
        const int seg = wave * 4 + i;                      // 16 segments of 1024 B
        g2l_b128(tab + seg * 512 + lane * 8, &afrags[seg * 512]);
    }

    // ---- chunk 0 DMA: 64 rows x 256 B, each wave 16 rows ----
    {
        const float* src0 = actn + (size_t)(wave * 16) * HW + p0 + lane;
#pragma unroll
        for (int i = 0; i < 16; ++i)
            g2l_b32(src0 + (size_t)i * HW, &chunkbuf[0][(wave * 16 + i) * CHUNK_STRIDE]);
    }
    __syncthreads();   // drains all DMA

    float4v acc[4][4];
#pragma unroll
    for (int ct = 0; ct < 4; ++ct)
#pragma unroll
        for (int pt = 0; pt < 4; ++pt)
            acc[ct][pt] = (float4v){0.f, 0.f, 0.f, 0.f};

    for (int c = 0; c < 4; ++c) {
        // prefetch chunk c+1 into the other buffer (stays in flight during compute)
        if (c < 3) {
            const float* srcn = actn + (size_t)((c + 1) * 64 + wave * 16) * HW + p0 + lane;
#pragma unroll
            for (int i = 0; i < 16; ++i)
                g2l_b32(srcn + (size_t)i * HW, &chunkbuf[(c + 1) & 1][(wave * 16 + i) * CHUNK_STRIDE]);
        }

        const float* cb = chunkbuf[c & 1];
#pragma unroll
        for (int half = 0; half < 2; ++half) {
            const int ag = c * 2 + half;                   // global K-step (0..7)
            // B fragments: 8 strided b32 reads + round + pack (fp32 -> bf16, round-half-up)
            short8 bfr[4];
#pragma unroll
            for (int pt = 0; pt < 4; ++pt) {
                const float* base = cb + (half * 32 + quad * 8) * CHUNK_STRIDE + pt * 16 + m;
                unsigned u[8];
#pragma unroll
                for (int j = 0; j < 8; ++j)
                    u[j] = __builtin_bit_cast(unsigned, base[j * CHUNK_STRIDE]) + 0x8000u;
                uint4 pk;
                pk.x = (u[0] >> 16) | (u[1] & 0xFFFF0000u);
                pk.y = (u[2] >> 16) | (u[3] & 0xFFFF0000u);
                pk.z = (u[4] >> 16) | (u[5] & 0xFFFF0000u);
                pk.w = (u[6] >> 16) | (u[7] & 0xFFFF0000u);
                bfr[pt] = __builtin_bit_cast(short8, pk);
            }
#pragma unroll
            for (int ct = 0; ct < 4; ++ct) {
                const int sp = ((2 * ag - ct) - 4 * wave) & 15;   // wave-uniform shift id
                const short8 af = *(const short8*)&afrags[sp * 512 + lane * 8];  // contiguous b128
#pragma unroll
                for (int pt = 0; pt < 4; ++pt)
                    acc[ct][pt] = __builtin_amdgcn_mfma_f32_16x16x32_bf16(
                        af, bfr[pt], acc[ct][pt], 0, 0, 0);
            }
        }
        if (c < 3) __syncthreads();   // drains chunk c+1 DMA; releases buf (c&1) for c+2
    }

    // ---- epilogue (verified in rounds 1-2): D layout col=lane&15, row=quad*4+r ----
#pragma unroll
    for (int ct = 0; ct < 4; ++ct) {
#pragma unroll
        for (int r = 0; r < 4; ++r) {
            const int cc = wave * 64 + ct * 16 + quad * 4 + r;
            float* op = outn + (size_t)cc * HW + p0;
#pragma unroll
            for (int pt = 0; pt < 4; ++pt) {
                op[pt * 16 + m] = acc[ct][pt][r];
            }
        }
    }
}

extern "C" void kernel_launch(void* const* d_in, const int* in_sizes, int n_in,
                              void* d_out, int out_size, void* d_ws, size_t ws_size,
                              hipStream_t stream) {
    const float* act = (const float*)d_in[0];
    const float* filt = (const float*)d_in[1];
    float* out = (float*)d_out;
    unsigned short* tab = (unsigned short*)d_ws;   // 16384 bytes used

    build_tab_kernel<<<1, 256, 0, stream>>>(filt, tab);
    toeplitz_gemm_kernel<<<2048, 256, 0, stream>>>(act, tab, out);
}